// Round 10
// baseline (91.185 us; speedup 1.0000x reference)
//
#include <hip/hip_runtime.h>
#include <hip/hip_bf16.h>
#include <math.h>

typedef __bf16 v8bf __attribute__((ext_vector_type(8)));
typedef float  v4f  __attribute__((ext_vector_type(4)));

#define GPTR(p) ((const __attribute__((address_space(1))) void*)(p))
#define LPTR(p) ((__attribute__((address_space(3))) void*)(p))

// ---------------- transpose helper (whole-block, dedicated LDS) -------------
__device__ __forceinline__ void transpose_tile(
    const float* __restrict__ W, __hip_bfloat16* __restrict__ Wt,
    int K, int N, int kt, int nt, int tid, float (*t)[33]) {
    int tx = tid & 31, ty = tid >> 5; // (32,8)
#pragma unroll
    for (int i = 0; i < 4; ++i)
        t[ty + i * 8][tx] = W[(size_t)(kt + ty + i * 8) * N + nt + tx];
    __syncthreads();
#pragma unroll
    for (int i = 0; i < 4; ++i)
        Wt[(size_t)(nt + ty + i * 8) * K + kt + tx] =
            __float2bfloat16(t[tx][ty + i * 8]);
}

// ---------------- prep1: x/y casts + W1 transposes (needed by L1 only) ------
struct Prep1Args {
    const float* x; const float* y;
    __hip_bfloat16* xb; __hip_bfloat16* yb;
    int nx4, ntot4;                      // cast counts (float4 units)
    const float* sW1; __hip_bfloat16* sW1t;
    const float* kW1; __hip_bfloat16* kW1t;
};

__global__ __launch_bounds__(256)
void prep1_k(Prep1Args a) {
    __shared__ float t[32][33];
    const int tid = threadIdx.x, bid = blockIdx.x;
    if (bid < 1280) {                    // casts
        int i = bid * 256 + tid;
        if (i >= a.ntot4) return;
        const float* src; __hip_bfloat16* dst; int j;
        if (i < a.nx4) { src = a.x; dst = a.xb; j = i; }
        else           { src = a.y; dst = a.yb; j = i - a.nx4; }
        float4 v = ((const float4*)src)[j];
        __hip_bfloat16 h[4] = {__float2bfloat16(v.x), __float2bfloat16(v.y),
                               __float2bfloat16(v.z), __float2bfloat16(v.w)};
        ((short4*)dst)[j] = *(short4*)h;
        return;
    }
    int ti = bid - 1280;
    if (ti < 256)        // sW1: 256x1024, 8x32 tiles
        transpose_tile(a.sW1, a.sW1t, 256, 1024,
                       (ti >> 5) * 32, (ti & 31) * 32, tid, t);
    else                 // kW1: 64x1024, 2x32 tiles
        transpose_tile(a.kW1, a.kW1t, 64, 1024,
                       ((ti - 256) >> 5) * 32, ((ti - 256) & 31) * 32, tid, t);
}

// ---------------- GEMM building blocks (128x128 tile, BK=64, 4 waves) -------
__device__ __forceinline__ void stage128(
    const __hip_bfloat16* __restrict__ A, const __hip_bfloat16* __restrict__ Bt,
    int lda, int ldb, int bm, int bn, int k0, int wid, int crow, int ccol,
    __hip_bfloat16* As, __hip_bfloat16* Bs) {
#pragma unroll
    for (int i = 0; i < 4; ++i) {
        int c = wid * 4 + i;
        __builtin_amdgcn_global_load_lds(
            GPTR(A + (size_t)(bm + c * 8 + crow) * lda + k0 + ccol),
            LPTR(As + c * 512), 16, 0, 0);
        __builtin_amdgcn_global_load_lds(
            GPTR(Bt + (size_t)(bn + c * 8 + crow) * ldb + k0 + ccol),
            LPTR(Bs + c * 512), 16, 0, 0);
    }
}

__device__ __forceinline__ void compute128(
    const __hip_bfloat16* As, const __hip_bfloat16* Bs,
    int lane, int wr, int wc, v4f acc[4][4]) {
#pragma unroll
    for (int kk = 0; kk < 64; kk += 32) {
        v8bf a[4], b[4];
#pragma unroll
        for (int i = 0; i < 4; ++i) {
            a[i] = *(const v8bf*)&As[(wr * 64 + i * 16 + (lane & 15)) * 64 + kk + (lane >> 4) * 8];
            b[i] = *(const v8bf*)&Bs[(wc * 64 + i * 16 + (lane & 15)) * 64 + kk + (lane >> 4) * 8];
        }
#pragma unroll
        for (int i = 0; i < 4; ++i)
#pragma unroll
            for (int j = 0; j < 4; ++j)
                acc[i][j] = __builtin_amdgcn_mfma_f32_16x16x32_bf16(
                    a[i], b[j], acc[i][j], 0, 0, 0);
    }
}

// ---------------- GEMM body: prefetch-dbuf (R9-proven), direct stores -------
__device__ __forceinline__ void gemm_body(
    const __hip_bfloat16* A, const __hip_bfloat16* Bt, const float* bias,
    __hip_bfloat16* C, int K, int wg,
    __hip_bfloat16* As0, __hip_bfloat16* As1,
    __hip_bfloat16* Bs0, __hip_bfloat16* Bs1) {
    const int rem = wg & 255;
    const int bm  = (rem >> 3) * 128;
    const int bn  = (rem & 7) * 128;
    const int tid = threadIdx.x, wid = tid >> 6, lane = tid & 63;
    const int wr = wid >> 1, wc = wid & 1;
    const int crow = lane >> 3, ccol = (lane & 7) * 8;
    const int nt = K >> 6;

    v4f acc[4][4] = {};
    stage128(A, Bt, K, K, bm, bn, 0, wid, crow, ccol, As0, Bs0);
    __syncthreads();
    for (int t = 0; t < nt; ++t) {
        const bool odd = t & 1;
        if (t + 1 < nt)
            stage128(A, Bt, K, K, bm, bn, (t + 1) * 64, wid, crow, ccol,
                     odd ? As0 : As1, odd ? Bs0 : Bs1);
        compute128(odd ? As1 : As0, odd ? Bs1 : Bs0, lane, wr, wc, acc);
        __syncthreads();
    }
#pragma unroll
    for (int i = 0; i < 4; ++i) {
        int rowb = bm + wr * 64 + i * 16 + (lane >> 4) * 4;
#pragma unroll
        for (int j = 0; j < 4; ++j) {
            int col = bn + wc * 64 + j * 16 + (lane & 15);
            float bv = bias[col];
#pragma unroll
            for (int r = 0; r < 4; ++r) {
                float v = fmaxf(acc[i][j][r] + bv, 0.f);
                C[(size_t)(rowb + r) * 1024 + col] = __float2bfloat16(v);
            }
        }
    }
}

// ---------------- L1 merged kernel: 512 GEMM blocks + 2304 transpose blocks -
// Transposes of W2/W3 (needed only by later launches) overlap the L1 GEMM.
struct L1Args {
    const __hip_bfloat16* A[2];
    const __hip_bfloat16* B[2];
    const float* bias[2];
    __hip_bfloat16* C[2];
    int K[2];
    const float* sW2; __hip_bfloat16* sW2t;
    const float* kW2; __hip_bfloat16* kW2t;
    const float* sW3; __hip_bfloat16* sW3t;
    const float* kW3; __hip_bfloat16* kW3t;
};

__global__ __launch_bounds__(256)
void l1_merged_k(L1Args args) {
    __shared__ __align__(16) __hip_bfloat16 As0[128 * 64], As1[128 * 64];
    __shared__ __align__(16) __hip_bfloat16 Bs0[128 * 64], Bs1[128 * 64];
    __shared__ float t[32][33];
    const int bid = blockIdx.x, tid = threadIdx.x;
    if (bid < 512) {
        const int wg = (bid & 7) * 64 + (bid >> 3);   // XCD swizzle (512/8=64)
        const int z  = wg >> 8;
        gemm_body(args.A[z], args.B[z], args.bias[z], args.C[z], args.K[z],
                  wg, As0, As1, Bs0, Bs1);
        return;
    }
    int ti = bid - 512;
    if (ti < 1024)        // sW2: 1024x1024, 32x32 tiles
        transpose_tile(args.sW2, args.sW2t, 1024, 1024,
                       (ti >> 5) * 32, (ti & 31) * 32, tid, t);
    else if (ti < 2048) { // kW2
        ti -= 1024;
        transpose_tile(args.kW2, args.kW2t, 1024, 1024,
                       (ti >> 5) * 32, (ti & 31) * 32, tid, t);
    } else if (ti < 2176) { // sW3: 1024x128, 32x4 tiles
        ti -= 2048;
        transpose_tile(args.sW3, args.sW3t, 1024, 128,
                       (ti >> 2) * 32, (ti & 3) * 32, tid, t);
    } else {              // kW3
        ti -= 2176;
        transpose_tile(args.kW3, args.kW3t, 1024, 128,
                       (ti >> 2) * 32, (ti & 3) * 32, tid, t);
    }
}

// ---------------- L2 GEMMs (both MLPs), pure GEMM launch --------------------
struct MlpArgs {
    const __hip_bfloat16* A[2];
    const __hip_bfloat16* B[2];
    const float* bias[2];
    __hip_bfloat16* C[2];
    int K[2];
};

__global__ __launch_bounds__(256)
void gemm_mlp_k(MlpArgs args) {
    __shared__ __align__(16) __hip_bfloat16 As0[128 * 64], As1[128 * 64];
    __shared__ __align__(16) __hip_bfloat16 Bs0[128 * 64], Bs1[128 * 64];
    const int bid = blockIdx.x;
    const int wg  = (bid & 7) * 64 + (bid >> 3);
    const int z   = wg >> 8;
    gemm_body(args.A[z], args.B[z], args.bias[z], args.C[z], args.K[z],
              wg, As0, As1, Bs0, Bs1);
}

// ---------------- L3 GEMM fused with bias + L2-normalize --------------------
// Tile 16x128 (BN=128 = full LAT), 512 blocks for 2x TLP (latency-bound).
__global__ __launch_bounds__(256)
void gemm_l3norm_k(const __hip_bfloat16* __restrict__ As_g0,
                   const __hip_bfloat16* __restrict__ As_g1,
                   const __hip_bfloat16* __restrict__ Bt0,
                   const __hip_bfloat16* __restrict__ Bt1,
                   const float* __restrict__ sb3, const float* __restrict__ kb3,
                   __hip_bfloat16* __restrict__ zxb,
                   __hip_bfloat16* __restrict__ zyb) {
    __shared__ __align__(16) __hip_bfloat16 As[2][16 * 64];   // 2x2KB
    __shared__ __align__(16) __hip_bfloat16 Bs[2][128 * 64];  // 2x16KB
    __shared__ float red[4][16];
    const int bid = blockIdx.x;
    const int wg  = (bid & 7) * 64 + (bid >> 3);  // 512/8=64 per XCD
    const int z   = wg >> 8;
    const int bm  = (wg & 255) * 16;

    const __hip_bfloat16* A  = z ? As_g1 : As_g0;
    const __hip_bfloat16* Bt = z ? Bt1 : Bt0;
    const float* bias = z ? kb3 : sb3;
    __hip_bfloat16* zout = z ? zyb : zxb;

    const int tid = threadIdx.x, wid = tid >> 6, lane = tid & 63;
    const int crow = lane >> 3, ccol = (lane & 7) * 8;

    auto stage = [&](int buf, int k0) {
        if (wid < 2)  // A tile: 2 chunks (16 rows)
            __builtin_amdgcn_global_load_lds(
                GPTR(A + (size_t)(bm + wid * 8 + crow) * 1024 + k0 + ccol),
                LPTR(&As[buf][wid * 512]), 16, 0, 0);
#pragma unroll
        for (int i = 0; i < 4; ++i) {
            int c = wid * 4 + i;
            __builtin_amdgcn_global_load_lds(
                GPTR(Bt + (size_t)(c * 8 + crow) * 1024 + k0 + ccol),
                LPTR(&Bs[buf][c * 512]), 16, 0, 0);
        }
    };
    auto compute = [&](int buf, v4f acc[2]) {
#pragma unroll
        for (int kk = 0; kk < 64; kk += 32) {
            v8bf a, b[2];
            a = *(const v8bf*)&As[buf][((lane & 15)) * 64 + kk + (lane >> 4) * 8];
#pragma unroll
            for (int j = 0; j < 2; ++j)
                b[j] = *(const v8bf*)&Bs[buf][(wid * 32 + j * 16 + (lane & 15)) * 64 + kk + (lane >> 4) * 8];
#pragma unroll
            for (int j = 0; j < 2; ++j)
                acc[j] = __builtin_amdgcn_mfma_f32_16x16x32_bf16(
                    a, b[j], acc[j], 0, 0, 0);
        }
    };

    v4f acc[2] = {};
    stage(0, 0);
    __syncthreads();
    for (int t = 0; t < 16; ++t) {
        const int cur = t & 1;
        if (t + 1 < 16) stage(cur ^ 1, (t + 1) * 64);
        compute(cur, acc);
        __syncthreads();
    }

    // bias + per-row sum of squares (this wave covers cols wid*32..wid*32+31)
    float val[2][4];
    float ssq[4];
#pragma unroll
    for (int r = 0; r < 4; ++r) ssq[r] = 0.f;
#pragma unroll
    for (int j = 0; j < 2; ++j) {
        int col = wid * 32 + j * 16 + (lane & 15);
        float bv = bias[col];
#pragma unroll
        for (int r = 0; r < 4; ++r) {
            float v = acc[j][r] + bv;
            val[j][r] = v;
            ssq[r] += v * v;
        }
    }
#pragma unroll
    for (int r = 0; r < 4; ++r) {
#pragma unroll
        for (int m = 1; m < 16; m <<= 1)
            ssq[r] += __shfl_xor(ssq[r], m, 64);
        if ((lane & 15) == 0)
            red[wid][(lane >> 4) * 4 + r] = ssq[r];
    }
    __syncthreads();
#pragma unroll
    for (int r = 0; r < 4; ++r) {
        int row = (lane >> 4) * 4 + r;
        float ss = red[0][row] + red[1][row] + red[2][row] + red[3][row];
        float inv = 1.0f / fmaxf(sqrtf(ss), 1e-12f);
#pragma unroll
        for (int j = 0; j < 2; ++j) {
            int col = wid * 32 + j * 16 + (lane & 15);
            zout[(size_t)(bm + row) * 128 + col] =
                __float2bfloat16(val[j][r] * inv);
        }
    }
}

// ---------------- scores GEMM + fused per-row partial exp-sums --------------
// scores in [-1,1] (cosine/TEMP), so lse = 1 + log(sum exp(s-1)) needs no max.
__global__ __launch_bounds__(256)
void gemm_scores_k(const __hip_bfloat16* __restrict__ zxb,
                   const __hip_bfloat16* __restrict__ zyb,
                   float* __restrict__ out, float* __restrict__ esum) {
    __shared__ __align__(16) __hip_bfloat16 As[128 * 64], Bs[128 * 64];
    __shared__ float rowsum[2][128];
    const int tid = threadIdx.x, wid = tid >> 6, lane = tid & 63;
    const int wr = wid >> 1, wc = wid & 1;
    const int bm = blockIdx.x * 128, bn = blockIdx.y * 128;
    const int crow = lane >> 3, ccol = (lane & 7) * 8;
    v4f acc[4][4] = {};
#pragma unroll
    for (int t = 0; t < 2; ++t) {
        stage128(zxb, zyb, 128, 128, bm, bn, t * 64, wid, crow, ccol, As, Bs);
        __syncthreads();
        compute128(As, Bs, lane, wr, wc, acc);
        __syncthreads();
    }
#pragma unroll
    for (int i = 0; i < 4; ++i) {
        int rowb = bm + wr * 64 + i * 16 + (lane >> 4) * 4;
#pragma unroll
        for (int r = 0; r < 4; ++r) {
            float s = 0.f;
#pragma unroll
            for (int j = 0; j < 4; ++j) {
                int col = bn + wc * 64 + j * 16 + (lane & 15);
                float v = acc[i][j][r];
                __builtin_nontemporal_store(v, &out[(size_t)(rowb + r) * 4096 + col]);
                s += __expf(v - 1.0f);
            }
#pragma unroll
            for (int m = 1; m < 16; m <<= 1) s += __shfl_xor(s, m, 64);
            if ((lane & 15) == 0)
                rowsum[wc][wr * 64 + i * 16 + (lane >> 4) * 4 + r] = s;
        }
    }
    __syncthreads();
    if (tid < 128)
        esum[(size_t)(bm + tid) * 32 + blockIdx.y] =
            rowsum[0][tid] + rowsum[1][tid];
}

// ---------------- mi from partial exp-sums + diag ---------------------------
__global__ __launch_bounds__(256)
void mi_k(const float* __restrict__ esum, const float* __restrict__ scores,
          float* __restrict__ mi) {
    int row = blockIdx.x * 256 + threadIdx.x;
    const float4* p = (const float4*)&esum[(size_t)row * 32];
    float s = 0.f;
#pragma unroll
    for (int i = 0; i < 8; ++i) { float4 v = p[i]; s += v.x + v.y + v.z + v.w; }
    float diag = scores[(size_t)row * 4096 + row];
    // mi = log(4096) + diag - (1 + log(sum))
    mi[row] = 8.317766166719343f + diag - 1.0f - logf(s);
}

// ---------------------------------------------------------------------------
extern "C" void kernel_launch(void* const* d_in, const int* in_sizes, int n_in,
                              void* d_out, int out_size, void* d_ws, size_t ws_size,
                              hipStream_t stream) {
    const float* x   = (const float*)d_in[0];
    const float* y   = (const float*)d_in[1];
    const float* sW1 = (const float*)d_in[2];
    const float* sb1 = (const float*)d_in[3];
    const float* sW2 = (const float*)d_in[4];
    const float* sb2 = (const float*)d_in[5];
    const float* sW3 = (const float*)d_in[6];
    const float* sb3 = (const float*)d_in[7];
    const float* kW1 = (const float*)d_in[8];
    const float* kb1 = (const float*)d_in[9];
    const float* kW2 = (const float*)d_in[10];
    const float* kb2 = (const float*)d_in[11];
    const float* kW3 = (const float*)d_in[12];
    const float* kb3 = (const float*)d_in[13];

    float* out = (float*)d_out;              // scores [4096][4096]
    float* mi  = out + (size_t)4096 * 4096;  // mi [4096]

    char* ws = (char*)d_ws;
    auto alloc = [&](size_t bytes) {
        char* p = ws;
        ws += (bytes + 255) & ~(size_t)255;
        return p;
    };
    __hip_bfloat16* xb   = (__hip_bfloat16*)alloc((size_t)4096 * 256 * 2);
    __hip_bfloat16* yb   = (__hip_bfloat16*)alloc((size_t)4096 * 64 * 2);
    __hip_bfloat16* sW1t = (__hip_bfloat16*)alloc((size_t)1024 * 256 * 2);
    __hip_bfloat16* sW2t = (__hip_bfloat16*)alloc((size_t)1024 * 1024 * 2);
    __hip_bfloat16* sW3t = (__hip_bfloat16*)alloc((size_t)128 * 1024 * 2);
    __hip_bfloat16* kW1t = (__hip_bfloat16*)alloc((size_t)1024 * 64 * 2);
    __hip_bfloat16* kW2t = (__hip_bfloat16*)alloc((size_t)1024 * 1024 * 2);
    __hip_bfloat16* kW3t = (__hip_bfloat16*)alloc((size_t)128 * 1024 * 2);
    __hip_bfloat16* h1s  = (__hip_bfloat16*)alloc((size_t)4096 * 1024 * 2);
    __hip_bfloat16* h1k  = (__hip_bfloat16*)alloc((size_t)4096 * 1024 * 2);
    __hip_bfloat16* h2s  = (__hip_bfloat16*)alloc((size_t)4096 * 1024 * 2);
    __hip_bfloat16* h2k  = (__hip_bfloat16*)alloc((size_t)4096 * 1024 * 2);
    float*          es   = (float*)alloc((size_t)4096 * 32 * 4);
    __hip_bfloat16* zxb  = (__hip_bfloat16*)alloc((size_t)4096 * 128 * 2);
    __hip_bfloat16* zyb  = (__hip_bfloat16*)alloc((size_t)4096 * 128 * 2);

    // K1: prep1 (casts + W1 transposes only)
    Prep1Args p1;
    p1.x = x; p1.y = y; p1.xb = xb; p1.yb = yb;
    p1.nx4 = 4096 * 256 / 4;
    p1.ntot4 = p1.nx4 + 4096 * 64 / 4;
    p1.sW1 = sW1; p1.sW1t = sW1t;
    p1.kW1 = kW1; p1.kW1t = kW1t;
    prep1_k<<<1280 + 256 + 64, 256, 0, stream>>>(p1);

    // K2: L1 GEMMs + overlapped W2/W3 transposes
    L1Args l1;
    l1.A[0] = xb;  l1.B[0] = sW1t; l1.bias[0] = sb1; l1.C[0] = h1s; l1.K[0] = 256;
    l1.A[1] = yb;  l1.B[1] = kW1t; l1.bias[1] = kb1; l1.C[1] = h1k; l1.K[1] = 64;
    l1.sW2 = sW2; l1.sW2t = sW2t;
    l1.kW2 = kW2; l1.kW2t = kW2t;
    l1.sW3 = sW3; l1.sW3t = sW3t;
    l1.kW3 = kW3; l1.kW3t = kW3t;
    l1_merged_k<<<512 + 2304, 256, 0, stream>>>(l1);

    // K3: L2 GEMMs (both MLPs)
    MlpArgs l2;
    l2.A[0] = h1s; l2.B[0] = sW2t; l2.bias[0] = sb2; l2.C[0] = h2s; l2.K[0] = 1024;
    l2.A[1] = h1k; l2.B[1] = kW2t; l2.bias[1] = kb2; l2.C[1] = h2k; l2.K[1] = 1024;
    gemm_mlp_k<<<512, 256, 0, stream>>>(l2);

    // K4: L3 GEMM + bias + normalize (both MLPs), 16-row tiles
    gemm_l3norm_k<<<512, 256, 0, stream>>>(
        h2s, h2k, sW3t, kW3t, sb3, kb3, zxb, zyb);

    // K5: scores GEMM + fused partial exp-sums
    gemm_scores_k<<<dim3(32, 32), 256, 0, stream>>>(zxb, zyb, out, es);

    // K6: mi
    mi_k<<<16, 256, 0, stream>>>(es, out, mi);
}